// Round 2
// baseline (462.259 us; speedup 1.0000x reference)
//
#include <hip/hip_runtime.h>

// LoRA forward, split into two streaming kernels through d_ws:
//   k1: tpart[m][p][r] = partial sums of x@B   (p = kquarter*4 + wave, 16 partials/row)
//   k2: out[m][n] = 2 * (sum_p tpart[m][p][r]) * A[r][n]
// x: [16384,4096] f32, B: [4096,8] f32, A: [8,4096] f32, out: [16384,4096] f32.
// Roofline: 268 MB read + 268 MB write @ ~6.3 TB/s ≈ 85 us.
// Fused predecessor (<=161 us per dispatch) was pinned by 128-VGPR frag (2 waves/SIMD)
// + read-phase/barrier/write-phase serialization. Here both kernels are high-occupancy
// pure streams with no inter-phase barrier.

#define KDIM    4096
#define NDIM    4096
#define M_TOTAL 16384
#define K1_ROWS 32      // rows per k1 block
#define K2_ROWS 32      // rows per k2 block
#define NPART   16      // 4 k-quarters x 4 waves

typedef __attribute__((ext_vector_type(4))) float float4v;

// ---------------- Kernel 1: x @ B -> tpart ----------------
// grid = 4 kquarters * (16384/32) row-groups = 2048 blocks, 256 threads.
// Thread t owns k = kb*1024 + 4t .. +3 (one float4 per row). B frag = 4x8 = 32 VGPR.
// Per row: 1 dwordx4 load, 32 FMA, 17-shfl folding reduce, 8-lane scatter store (32 B).
__global__ __launch_bounds__(256, 4) void lora_xb(
    const float* __restrict__ x,
    const float* __restrict__ B,
    float* __restrict__ tpart)
{
    const int t    = threadIdx.x;
    const int lane = t & 63;
    const int wave = t >> 6;
    const int bid  = blockIdx.x;
    const int kb   = bid & 3;                 // k quarter
    const int rg   = bid >> 2;                // row group
    const long m0  = (long)rg * K1_ROWS;
    const int kbase = kb * 1024 + 4 * t;      // this thread's 4 k values
    const int p    = kb * 4 + wave;           // partial slot for this wave

    // B fragment: B[kbase+i][r] (B row-major [4096][8] => two float4 per k)
    float fb[4][8];
    {
        const float4v* Bv = (const float4v*)B;
#pragma unroll
        for (int i = 0; i < 4; ++i) {
            float4v b0 = Bv[2 * (kbase + i)];
            float4v b1 = Bv[2 * (kbase + i) + 1];
#pragma unroll
            for (int r = 0; r < 4; ++r) { fb[i][r] = b0[r]; fb[i][4 + r] = b1[r]; }
        }
    }

    // Depth-4 row prefetch ping-pong (static indices only — no scratch).
    float4v c0, c1, c2, c3;
    c0 = *(const float4v*)(x + (m0 + 0) * KDIM + kbase);
    c1 = *(const float4v*)(x + (m0 + 1) * KDIM + kbase);
    c2 = *(const float4v*)(x + (m0 + 2) * KDIM + kbase);
    c3 = *(const float4v*)(x + (m0 + 3) * KDIM + kbase);

    auto body = [&](float4v& cb, int rr) {
        float acc[8];
#pragma unroll
        for (int r = 0; r < 8; ++r) acc[r] = 0.0f;
#pragma unroll
        for (int i = 0; i < 4; ++i) {
            const float xv = cb[i];
#pragma unroll
            for (int r = 0; r < 8; ++r)
                acc[r] = fmaf(xv, fb[i][r], acc[r]);
        }
        // prefetch row rr+4 into the buffer just consumed (WAR-safe)
        const int nr = rr + 4;
        if (nr < K1_ROWS)
            cb = *(const float4v*)(x + (m0 + nr) * KDIM + kbase);

        // Folding reduce: 17 shfls. After stages A-C, value index
        // r = 4*bit5 + 2*bit4 + bit3 of the lane; stages D-F sum lane bits 2..0.
        float s[8];
#pragma unroll
        for (int r = 0; r < 8; ++r) s[r] = __shfl_xor(acc[r], 32, 64);
        const bool b5 = (lane & 32) != 0;
        float v[4];
#pragma unroll
        for (int j = 0; j < 4; ++j)
            v[j] = b5 ? (acc[4 + j] + s[4 + j]) : (acc[j] + s[j]);
        float sb[4];
#pragma unroll
        for (int j = 0; j < 4; ++j) sb[j] = __shfl_xor(v[j], 16, 64);
        const bool b4 = (lane & 16) != 0;
        float w0 = b4 ? (v[2] + sb[2]) : (v[0] + sb[0]);
        float w1 = b4 ? (v[3] + sb[3]) : (v[1] + sb[1]);
        float sc0 = __shfl_xor(w0, 8, 64);
        float sc1 = __shfl_xor(w1, 8, 64);
        const bool b3 = (lane & 8) != 0;
        float u = b3 ? (w1 + sc1) : (w0 + sc0);
        u += __shfl_xor(u, 4, 64);
        u += __shfl_xor(u, 2, 64);
        u += __shfl_xor(u, 1, 64);
        if ((lane & 7) == 0) {
            const int r = (((lane >> 5) & 1) << 2) | (((lane >> 4) & 1) << 1) |
                          ((lane >> 3) & 1);
            // 8 lanes write 8 consecutive dwords (one 32 B segment)
            tpart[((m0 + rr) * NPART + p) * 8 + r] = u;
        }
    };

#pragma unroll 1
    for (int rp = 0; rp < K1_ROWS; rp += 4) {
        body(c0, rp);
        body(c1, rp + 1);
        body(c2, rp + 2);
        body(c3, rp + 3);
    }
}

// ---------------- Kernel 2: out = 2 * t @ A ----------------
// grid = 4 col-quarters * (16384/32) row-groups = 2048 blocks, 256 threads.
// Thread t owns n = nb*1024 + 4t .. +3. A frag = 8 float4 = 32 VGPR.
// Per row: 8 LDS broadcast reads, 32 FMA, 1 dwordx4 store. Write-bound.
__global__ __launch_bounds__(256, 4) void lora_ta(
    const float* __restrict__ tpart,
    const float* __restrict__ A,
    float* __restrict__ out)
{
    __shared__ float tl[K2_ROWS][8];

    const int t   = threadIdx.x;
    const int bid = blockIdx.x;
    const int nb  = bid & 3;               // column quarter
    const int rg  = bid >> 2;              // row group
    const long m0 = (long)rg * K2_ROWS;
    const int n0  = nb * 1024 + 4 * t;

    // Issue A-frag loads first (L2/L3-resident, reused over 32 rows).
    float4v fa[8];
#pragma unroll
    for (int r = 0; r < 8; ++r)
        fa[r] = *(const float4v*)(A + r * NDIM + n0);

    // Sum the 16 partials per (row, r): 256 threads = 32 rows x 8 ranks.
    {
        const int mm = t >> 3, r = t & 7;
        const float* tp = tpart + ((m0 + mm) * NPART) * 8 + r;
        float s = 0.0f;
#pragma unroll
        for (int pp = 0; pp < NPART; ++pp) s += tp[pp * 8];
        tl[mm][r] = 2.0f * s;
    }
    __syncthreads();

#pragma unroll 2
    for (int mm = 0; mm < K2_ROWS; ++mm) {
        float tv[8];
#pragma unroll
        for (int r = 0; r < 8; ++r) tv[r] = tl[mm][r];   // LDS broadcast (free)
        float4v o;
#pragma unroll
        for (int i = 0; i < 4; ++i) {
            float s = 0.0f;
#pragma unroll
            for (int r = 0; r < 8; ++r)
                s = fmaf(tv[r], fa[r][i], s);
            o[i] = s;
        }
        *(float4v*)(out + (m0 + mm) * NDIM + n0) = o;
    }
}

extern "C" void kernel_launch(void* const* d_in, const int* in_sizes, int n_in,
                              void* d_out, int out_size, void* d_ws, size_t ws_size,
                              hipStream_t stream) {
    const float* x = (const float*)d_in[0];  // [4,4096,4096] -> [16384,4096]
    const float* A = (const float*)d_in[1];  // [8,4096]
    const float* B = (const float*)d_in[2];  // [4096,8]
    float* out = (float*)d_out;
    float* tpart = (float*)d_ws;             // needs 16384*16*8*4 = 8 MB

    (void)in_sizes; (void)n_in; (void)out_size; (void)ws_size;

    dim3 g1(4 * (M_TOTAL / K1_ROWS));   // 2048 blocks
    dim3 g2(4 * (M_TOTAL / K2_ROWS));   // 2048 blocks
    lora_xb<<<g1, 256, 0, stream>>>(x, B, tpart);
    lora_ta<<<g2, 256, 0, stream>>>(tpart, A, out);
}

// Round 3
// 435.413 us; speedup vs baseline: 1.0617x; 1.0617x over previous
//
#include <hip/hip_runtime.h>

// LoRA forward, fused, all fp32:
//   out[m,n] = 2 * sum_r (sum_k x[m,k] * B[k,r]) * A[r,n]
// x: [16384,4096] f32, B: [4096,8] f32, A: [8,4096] f32, out: [16384,4096] f32.
// Roofline: 268 MB read + 268 MB write @ ~6.3-6.5 TB/s ≈ 82-85 us.
// History: fused 16-col/thread (128-VGPR frag, 2 waves/SIMD) = 445 us total window;
// 2-kernel split = 462 (launch + ws traffic penalty). This version: fused,
// 512-thread blocks, 8 cols/thread -> 64-VGPR frag -> 4 waves/SIMD (2x occupancy),
// nontemporal x loads / out stores (536 MB stream shouldn't churn 32 MB L2).

#define NT      512
#define ROWS    16
#define KDIM    4096
#define NDIM    4096
#define M_TOTAL 16384

typedef __attribute__((ext_vector_type(4))) float float4v;

__global__ __launch_bounds__(NT, 4) void lora_fused(
    const float* __restrict__ x,
    const float* __restrict__ A,
    const float* __restrict__ B,
    float* __restrict__ out)
{
    __shared__ float part[ROWS][8][8];  // per-wave rank partials (8 waves)
    __shared__ float tl[ROWS][8];       // final 2*t[row][r]

    const int t = threadIdx.x;
    const int lane = t & 63;
    const int wave = t >> 6;
    const long m_base = (long)blockIdx.x * ROWS;

    // frag[j][r]: phase 1 = B[k(j)][r]; phase 2 (reused) = A[r][n(j)].
    // j = 4*q + i  ->  k(j) = n(j) = q*2048 + 4*t + i   (q in 0..1, i in 0..3)
    // 8 cols/thread -> 64 VGPR fragment (vs 128 before): 4 waves/SIMD.
    float frag[8][8];

    {   // B fragment: 8 rows of B, each 8 f32 = two float4.
        const float4v* Bv = (const float4v*)B;
#pragma unroll
        for (int q = 0; q < 2; ++q)
#pragma unroll
            for (int i = 0; i < 4; ++i) {
                const int k = q * 2048 + 4 * t + i;
                float4v b0 = Bv[2 * k];
                float4v b1 = Bv[2 * k + 1];
                const int j = 4 * q + i;
#pragma unroll
                for (int r = 0; r < 4; ++r) {
                    frag[j][r]     = b0[r];
                    frag[j][4 + r] = b1[r];
                }
            }
    }

    // ---------------- Phase 1: t = x @ B ----------------
    // Per row each thread loads 2 float4 (8 floats). Depth-2 ping-pong.
    float4v cA[2], cB[2];
    {
        const float4v* x0 = (const float4v*)(x + m_base * KDIM);
        const float4v* x1 = (const float4v*)(x + (m_base + 1) * KDIM);
#pragma unroll
        for (int q = 0; q < 2; ++q) {
            cA[q] = __builtin_nontemporal_load(&x0[q * 512 + t]);
            cB[q] = __builtin_nontemporal_load(&x1[q * 512 + t]);
        }
    }

    auto p1_body = [&](float4v (&cb)[2], int rr) {
        float acc[8];
#pragma unroll
        for (int r = 0; r < 8; ++r) acc[r] = 0.0f;
#pragma unroll
        for (int q = 0; q < 2; ++q)
#pragma unroll
            for (int i = 0; i < 4; ++i) {
                const float xv = cb[q][i];
                const int j = 4 * q + i;
#pragma unroll
                for (int r = 0; r < 8; ++r)
                    acc[r] = fmaf(xv, frag[j][r], acc[r]);
            }

        // Prefetch row rr+2 into the buffer just consumed (WAR-safe).
        const int nr = rr + 2;
        if (nr < ROWS) {
            const float4v* xn = (const float4v*)(x + (m_base + nr) * KDIM);
#pragma unroll
            for (int q = 0; q < 2; ++q)
                cb[q] = __builtin_nontemporal_load(&xn[q * 512 + t]);
        }

        // Folding reduce: 17 shfls. After stages A-C lane (l&7)==0 holds the
        // wave sum for r = 4*bit5 + 2*bit4 + bit3.
        float s[8];
#pragma unroll
        for (int r = 0; r < 8; ++r) s[r] = __shfl_xor(acc[r], 32, 64);
        const bool b5 = (lane & 32) != 0;
        float v[4];
#pragma unroll
        for (int j = 0; j < 4; ++j)
            v[j] = b5 ? (acc[4 + j] + s[4 + j]) : (acc[j] + s[j]);
        float sb[4];
#pragma unroll
        for (int j = 0; j < 4; ++j) sb[j] = __shfl_xor(v[j], 16, 64);
        const bool b4 = (lane & 16) != 0;
        float w0 = b4 ? (v[2] + sb[2]) : (v[0] + sb[0]);
        float w1 = b4 ? (v[3] + sb[3]) : (v[1] + sb[1]);
        float sc0 = __shfl_xor(w0, 8, 64);
        float sc1 = __shfl_xor(w1, 8, 64);
        const bool b3 = (lane & 8) != 0;
        float u = b3 ? (w1 + sc1) : (w0 + sc0);
        u += __shfl_xor(u, 4, 64);
        u += __shfl_xor(u, 2, 64);
        u += __shfl_xor(u, 1, 64);
        if ((lane & 7) == 0) {
            const int r = (((lane >> 5) & 1) << 2) | (((lane >> 4) & 1) << 1) |
                          ((lane >> 3) & 1);
            part[rr][wave][r] = u;
        }
    };

#pragma unroll 1
    for (int rp = 0; rp < ROWS; rp += 2) {
        p1_body(cA, rp);
        p1_body(cB, rp + 1);
    }
    __syncthreads();

    if (t < ROWS * 8) {
        const int rr = t >> 3, r = t & 7;
        float s = 0.0f;
#pragma unroll
        for (int w = 0; w < 8; ++w) s += part[rr][w][r];
        tl[rr][r] = 2.0f * s;
    }

    {   // A fragment into the same register array (L2-resident, 128 KiB).
        const float4v* Av = (const float4v*)A;
#pragma unroll
        for (int r = 0; r < 8; ++r)
#pragma unroll
            for (int q = 0; q < 2; ++q) {
                float4v a = Av[r * 1024 + q * 512 + t];
#pragma unroll
                for (int i = 0; i < 4; ++i)
                    frag[4 * q + i][r] = a[i];
            }
    }
    __syncthreads();

    // ---------------- Phase 2: out = (2t) @ A ----------------
#pragma unroll 2
    for (int rr = 0; rr < ROWS; ++rr) {
        float tv[8];
#pragma unroll
        for (int r = 0; r < 8; ++r) tv[r] = tl[rr][r];  // LDS broadcast

        float* orow = out + (m_base + rr) * NDIM;
#pragma unroll
        for (int q = 0; q < 2; ++q) {
            float4v o;
#pragma unroll
            for (int i = 0; i < 4; ++i) {
                float s2 = 0.0f;
#pragma unroll
                for (int r = 0; r < 8; ++r)
                    s2 = fmaf(tv[r], frag[4 * q + i][r], s2);
                o[i] = s2;
            }
            __builtin_nontemporal_store(o, (float4v*)(orow + q * 2048 + 4 * t));
        }
    }
}

extern "C" void kernel_launch(void* const* d_in, const int* in_sizes, int n_in,
                              void* d_out, int out_size, void* d_ws, size_t ws_size,
                              hipStream_t stream) {
    const float* x = (const float*)d_in[0];  // [4,4096,4096] -> [16384,4096]
    const float* A = (const float*)d_in[1];  // [8,4096]
    const float* B = (const float*)d_in[2];  // [4096,8]
    float* out = (float*)d_out;

    (void)in_sizes; (void)n_in; (void)out_size; (void)d_ws; (void)ws_size;

    dim3 grid(M_TOTAL / ROWS);
    lora_fused<<<grid, NT, 0, stream>>>(x, A, B, out);
}

// Round 4
// 427.509 us; speedup vs baseline: 1.0813x; 1.0185x over previous
//
#include <hip/hip_runtime.h>

// LoRA forward, fused, all fp32:
//   out[m,n] = 2 * sum_r (sum_k x[m,k] * B[k,r]) * A[r,n]
// x: [16384,4096] f32, B: [4096,8] f32, A: [8,4096] f32, out: [16384,4096] f32.
// Kernel roofline: 268 MB read + 268 MB write @ ~6.5 TB/s ≈ 82.5 us.
// Window decomposition (rounds 0-2): ~330 us harness fills + ~105 us kernel.
// R2 (512 thr, 8 cols/thread, 64-VGPR frag, 4 waves/SIMD, NT ld/st) = 435.4 total.
// This round: ROWS 16->32 => 512 blocks = exactly one residency round
// (256 CU x 2 blocks/CU): per-block fixed costs (frag loads, 2 barriers,
// tl stage, phase-transition drain) halved, no inter-round tail.

#define NT      512
#define ROWS    32
#define KDIM    4096
#define NDIM    4096
#define M_TOTAL 16384

typedef __attribute__((ext_vector_type(4))) float float4v;

__global__ __launch_bounds__(NT, 4) void lora_fused(
    const float* __restrict__ x,
    const float* __restrict__ A,
    const float* __restrict__ B,
    float* __restrict__ out)
{
    __shared__ float part[ROWS][8][8];  // per-wave rank partials (8 waves) — 8 KB
    __shared__ float tl[ROWS][8];       // final 2*t[row][r] — 1 KB

    const int t = threadIdx.x;
    const int lane = t & 63;
    const int wave = t >> 6;
    const long m_base = (long)blockIdx.x * ROWS;

    // frag[j][r]: phase 1 = B[k(j)][r]; phase 2 (reused) = A[r][n(j)].
    // j = 4*q + i  ->  k(j) = n(j) = q*2048 + 4*t + i   (q in 0..1, i in 0..3)
    // 8 cols/thread -> 64 VGPR fragment: 4 waves/SIMD.
    float frag[8][8];

    {   // B fragment: 8 rows of B, each 8 f32 = two float4.
        const float4v* Bv = (const float4v*)B;
#pragma unroll
        for (int q = 0; q < 2; ++q)
#pragma unroll
            for (int i = 0; i < 4; ++i) {
                const int k = q * 2048 + 4 * t + i;
                float4v b0 = Bv[2 * k];
                float4v b1 = Bv[2 * k + 1];
                const int j = 4 * q + i;
#pragma unroll
                for (int r = 0; r < 4; ++r) {
                    frag[j][r]     = b0[r];
                    frag[j][4 + r] = b1[r];
                }
            }
    }

    // ---------------- Phase 1: t = x @ B ----------------
    // Per row each thread loads 2 float4 (8 floats). Depth-2 ping-pong.
    float4v cA[2], cB[2];
    {
        const float4v* x0 = (const float4v*)(x + m_base * KDIM);
        const float4v* x1 = (const float4v*)(x + (m_base + 1) * KDIM);
#pragma unroll
        for (int q = 0; q < 2; ++q) {
            cA[q] = __builtin_nontemporal_load(&x0[q * 512 + t]);
            cB[q] = __builtin_nontemporal_load(&x1[q * 512 + t]);
        }
    }

    auto p1_body = [&](float4v (&cb)[2], int rr) {
        float acc[8];
#pragma unroll
        for (int r = 0; r < 8; ++r) acc[r] = 0.0f;
#pragma unroll
        for (int q = 0; q < 2; ++q)
#pragma unroll
            for (int i = 0; i < 4; ++i) {
                const float xv = cb[q][i];
                const int j = 4 * q + i;
#pragma unroll
                for (int r = 0; r < 8; ++r)
                    acc[r] = fmaf(xv, frag[j][r], acc[r]);
            }

        // Prefetch row rr+2 into the buffer just consumed (WAR-safe).
        const int nr = rr + 2;
        if (nr < ROWS) {
            const float4v* xn = (const float4v*)(x + (m_base + nr) * KDIM);
#pragma unroll
            for (int q = 0; q < 2; ++q)
                cb[q] = __builtin_nontemporal_load(&xn[q * 512 + t]);
        }

        // Folding reduce: 17 shfls. After stages A-C lane (l&7)==0 holds the
        // wave sum for r = 4*bit5 + 2*bit4 + bit3.
        float s[8];
#pragma unroll
        for (int r = 0; r < 8; ++r) s[r] = __shfl_xor(acc[r], 32, 64);
        const bool b5 = (lane & 32) != 0;
        float v[4];
#pragma unroll
        for (int j = 0; j < 4; ++j)
            v[j] = b5 ? (acc[4 + j] + s[4 + j]) : (acc[j] + s[j]);
        float sb[4];
#pragma unroll
        for (int j = 0; j < 4; ++j) sb[j] = __shfl_xor(v[j], 16, 64);
        const bool b4 = (lane & 16) != 0;
        float w0 = b4 ? (v[2] + sb[2]) : (v[0] + sb[0]);
        float w1 = b4 ? (v[3] + sb[3]) : (v[1] + sb[1]);
        float sc0 = __shfl_xor(w0, 8, 64);
        float sc1 = __shfl_xor(w1, 8, 64);
        const bool b3 = (lane & 8) != 0;
        float u = b3 ? (w1 + sc1) : (w0 + sc0);
        u += __shfl_xor(u, 4, 64);
        u += __shfl_xor(u, 2, 64);
        u += __shfl_xor(u, 1, 64);
        if ((lane & 7) == 0) {
            const int r = (((lane >> 5) & 1) << 2) | (((lane >> 4) & 1) << 1) |
                          ((lane >> 3) & 1);
            part[rr][wave][r] = u;
        }
    };

#pragma unroll 1
    for (int rp = 0; rp < ROWS; rp += 2) {
        p1_body(cA, rp);
        p1_body(cB, rp + 1);
    }
    __syncthreads();

    if (t < ROWS * 8) {
        const int rr = t >> 3, r = t & 7;
        float s = 0.0f;
#pragma unroll
        for (int w = 0; w < 8; ++w) s += part[rr][w][r];
        tl[rr][r] = 2.0f * s;
    }

    {   // A fragment into the same register array (L2-resident, 128 KiB).
        const float4v* Av = (const float4v*)A;
#pragma unroll
        for (int r = 0; r < 8; ++r)
#pragma unroll
            for (int q = 0; q < 2; ++q) {
                float4v a = Av[r * 1024 + q * 512 + t];
#pragma unroll
                for (int i = 0; i < 4; ++i)
                    frag[4 * q + i][r] = a[i];
            }
    }
    __syncthreads();

    // ---------------- Phase 2: out = (2t) @ A ----------------
#pragma unroll 2
    for (int rr = 0; rr < ROWS; ++rr) {
        float tv[8];
#pragma unroll
        for (int r = 0; r < 8; ++r) tv[r] = tl[rr][r];  // LDS broadcast

        float* orow = out + (m_base + rr) * NDIM;
#pragma unroll
        for (int q = 0; q < 2; ++q) {
            float4v o;
#pragma unroll
            for (int i = 0; i < 4; ++i) {
                float s2 = 0.0f;
#pragma unroll
                for (int r = 0; r < 8; ++r)
                    s2 = fmaf(tv[r], frag[4 * q + i][r], s2);
                o[i] = s2;
            }
            __builtin_nontemporal_store(o, (float4v*)(orow + q * 2048 + 4 * t));
        }
    }
}

extern "C" void kernel_launch(void* const* d_in, const int* in_sizes, int n_in,
                              void* d_out, int out_size, void* d_ws, size_t ws_size,
                              hipStream_t stream) {
    const float* x = (const float*)d_in[0];  // [4,4096,4096] -> [16384,4096]
    const float* A = (const float*)d_in[1];  // [8,4096]
    const float* B = (const float*)d_in[2];  // [4096,8]
    float* out = (float*)d_out;

    (void)in_sizes; (void)n_in; (void)out_size; (void)d_ws; (void)ws_size;

    dim3 grid(M_TOTAL / ROWS);   // 512 blocks = one full residency round
    lora_fused<<<grid, NT, 0, stream>>>(x, A, B, out);
}

// Round 5
// 427.255 us; speedup vs baseline: 1.0819x; 1.0006x over previous
//
#include <hip/hip_runtime.h>

// LoRA forward, fused, all fp32:
//   out[m,n] = 2 * sum_r (sum_k x[m,k] * B[k,r]) * A[r,n]
// x: [16384,4096] f32, B: [4096,8] f32, A: [8,4096] f32, out: [16384,4096] f32.
// Kernel roofline: 268 MB read + 268 MB write @ 6.29 TB/s (measured copy) = 85.4 us.
// Window = ~330 us harness fills + kernel. R3 (ROWS=32, 512 blocks, 1 residency
// round) = 427.5 total => kernel ~97 us (88% of copy ceiling).
// This round: attack the phase-1 serial DS reduce chain:
//  - stage A (xor 32) via v_permlane32_swap (4 VALU ops, no DS, no lgkmcnt)
//  - both rows of a ping-pong pair reduced with adjacent, independent chains
//  - A-fragment load hoisted before the first barrier.

#define NT      512
#define ROWS    32
#define KDIM    4096
#define NDIM    4096
#define M_TOTAL 16384

typedef __attribute__((ext_vector_type(4))) float float4v;

// v_permlane32_swap_b32: ret0 = {a.lo, b.lo}, ret1 = {a.hi, b.hi} (32-lane rows).
// ret0+ret1: lane l<32 -> a[l]+a[l^32]; lane l>=32 -> b[l]+b[l^32].
static __device__ inline float permfold(float a, float b) {
    typedef __attribute__((ext_vector_type(2))) unsigned int uint2v;
    uint2v r = __builtin_amdgcn_permlane32_swap(
        __float_as_uint(a), __float_as_uint(b), false, false);
    return __uint_as_float(r.x) + __uint_as_float(r.y);
}

__global__ __launch_bounds__(NT, 4) void lora_fused(
    const float* __restrict__ x,
    const float* __restrict__ A,
    const float* __restrict__ B,
    float* __restrict__ out)
{
    __shared__ float part[ROWS][8][8];  // per-wave rank partials (8 waves) — 8 KB
    __shared__ float tl[ROWS][8];       // final 2*t[row][r] — 1 KB

    const int t = threadIdx.x;
    const int lane = t & 63;
    const int wave = t >> 6;
    const long m_base = (long)blockIdx.x * ROWS;

    // frag[j][r]: phase 1 = B[k(j)][r]; phase 2 (reused) = A[r][n(j)].
    // j = 4*q + i  ->  k(j) = n(j) = q*2048 + 4*t + i   (q in 0..1, i in 0..3)
    float frag[8][8];

    {   // B fragment: 8 rows of B, each 8 f32 = two float4.
        const float4v* Bv = (const float4v*)B;
#pragma unroll
        for (int q = 0; q < 2; ++q)
#pragma unroll
            for (int i = 0; i < 4; ++i) {
                const int k = q * 2048 + 4 * t + i;
                float4v b0 = Bv[2 * k];
                float4v b1 = Bv[2 * k + 1];
                const int j = 4 * q + i;
#pragma unroll
                for (int r = 0; r < 4; ++r) {
                    frag[j][r]     = b0[r];
                    frag[j][4 + r] = b1[r];
                }
            }
    }

    // ---------------- Phase 1: t = x @ B ----------------
    float4v cA[2], cB[2];
    {
        const float4v* x0 = (const float4v*)(x + m_base * KDIM);
        const float4v* x1 = (const float4v*)(x + (m_base + 1) * KDIM);
#pragma unroll
        for (int q = 0; q < 2; ++q) {
            cA[q] = __builtin_nontemporal_load(&x0[q * 512 + t]);
            cB[q] = __builtin_nontemporal_load(&x1[q * 512 + t]);
        }
    }

    // Reduce tail (after permlane stage A): 9 shfls per row, two rows
    // interleaved so the independent DS chains overlap.
    auto reduce_tail = [&](float (&v)[4], int rr) {
        float sb[4];
#pragma unroll
        for (int j = 0; j < 4; ++j) sb[j] = __shfl_xor(v[j], 16, 64);
        const bool b4 = (lane & 16) != 0;
        float w0 = b4 ? (v[2] + sb[2]) : (v[0] + sb[0]);
        float w1 = b4 ? (v[3] + sb[3]) : (v[1] + sb[1]);
        float sc0 = __shfl_xor(w0, 8, 64);
        float sc1 = __shfl_xor(w1, 8, 64);
        const bool b3 = (lane & 8) != 0;
        float u = b3 ? (w1 + sc1) : (w0 + sc0);
        u += __shfl_xor(u, 4, 64);
        u += __shfl_xor(u, 2, 64);
        u += __shfl_xor(u, 1, 64);
        if ((lane & 7) == 0) {
            const int r = (((lane >> 5) & 1) << 2) | (((lane >> 4) & 1) << 1) |
                          ((lane >> 3) & 1);
            part[rr][wave][r] = u;
        }
    };

#pragma unroll 1
    for (int rp = 0; rp < ROWS; rp += 2) {
        float accA[8], accB[8];
#pragma unroll
        for (int r = 0; r < 8; ++r) { accA[r] = 0.0f; accB[r] = 0.0f; }
#pragma unroll
        for (int q = 0; q < 2; ++q)
#pragma unroll
            for (int i = 0; i < 4; ++i) {
                const int j = 4 * q + i;
                const float xa = cA[q][i];
                const float xb = cB[q][i];
#pragma unroll
                for (int r = 0; r < 8; ++r) {
                    accA[r] = fmaf(xa, frag[j][r], accA[r]);
                    accB[r] = fmaf(xb, frag[j][r], accB[r]);
                }
            }

        // Prefetch rows rp+2, rp+3 into the buffers just consumed (WAR-safe).
        if (rp + 2 < ROWS) {
            const float4v* xn0 = (const float4v*)(x + (m_base + rp + 2) * KDIM);
            const float4v* xn1 = (const float4v*)(x + (m_base + rp + 3) * KDIM);
#pragma unroll
            for (int q = 0; q < 2; ++q) {
                cA[q] = __builtin_nontemporal_load(&xn0[q * 512 + t]);
                cB[q] = __builtin_nontemporal_load(&xn1[q * 512 + t]);
            }
        }

        // Stage A (xor 32) via permlane32_swap: pure VALU, both rows.
        float vA[4], vB[4];
#pragma unroll
        for (int j = 0; j < 4; ++j) {
            vA[j] = permfold(accA[j], accA[4 + j]);
            vB[j] = permfold(accB[j], accB[4 + j]);
        }
        // Remaining DS stages, adjacent independent chains.
        reduce_tail(vA, rp);
        reduce_tail(vB, rp + 1);
    }

    {   // A fragment (L2-resident): hoisted before the barrier — B-frag is dead,
        // the 8 loads hide under the barrier + tl stage.
        const float4v* Av = (const float4v*)A;
#pragma unroll
        for (int r = 0; r < 8; ++r)
#pragma unroll
            for (int q = 0; q < 2; ++q) {
                float4v a = Av[r * 1024 + q * 512 + t];
#pragma unroll
                for (int i = 0; i < 4; ++i)
                    frag[4 * q + i][r] = a[i];
            }
    }
    __syncthreads();

    if (t < ROWS * 8) {
        const int rr = t >> 3, r = t & 7;
        float s = 0.0f;
#pragma unroll
        for (int w = 0; w < 8; ++w) s += part[rr][w][r];
        tl[rr][r] = 2.0f * s;
    }
    __syncthreads();

    // ---------------- Phase 2: out = (2t) @ A ----------------
#pragma unroll 2
    for (int rr = 0; rr < ROWS; ++rr) {
        float tv[8];
#pragma unroll
        for (int r = 0; r < 8; ++r) tv[r] = tl[rr][r];  // LDS broadcast

        float* orow = out + (m_base + rr) * NDIM;
#pragma unroll
        for (int q = 0; q < 2; ++q) {
            float4v o;
#pragma unroll
            for (int i = 0; i < 4; ++i) {
                float s2 = 0.0f;
#pragma unroll
                for (int r = 0; r < 8; ++r)
                    s2 = fmaf(tv[r], frag[4 * q + i][r], s2);
                o[i] = s2;
            }
            __builtin_nontemporal_store(o, (float4v*)(orow + q * 2048 + 4 * t));
        }
    }
}

extern "C" void kernel_launch(void* const* d_in, const int* in_sizes, int n_in,
                              void* d_out, int out_size, void* d_ws, size_t ws_size,
                              hipStream_t stream) {
    const float* x = (const float*)d_in[0];  // [4,4096,4096] -> [16384,4096]
    const float* A = (const float*)d_in[1];  // [8,4096]
    const float* B = (const float*)d_in[2];  // [4096,8]
    float* out = (float*)d_out;

    (void)in_sizes; (void)n_in; (void)out_size; (void)d_ws; (void)ws_size;

    dim3 grid(M_TOTAL / ROWS);   // 512 blocks = one full residency round
    lora_fused<<<grid, NT, 0, stream>>>(x, A, B, out);
}